// Round 3
// 146.747 us; speedup vs baseline: 1.0072x; 1.0072x over previous
//
#include <hip/hip_runtime.h>

// Kernel 1: per-block partial sums of squared differences.
// n4 = 4,192,256 float4 pairs = 2047 blocks x 256 threads x 8 pairs EXACTLY
// (2047*2048 = 4,192,256) -> no bounds checks, no OOB.
//
// MLP fix (no-asm variant): the VGPR=32 build had the compiler sink the
// t-loads into the compute loop => only ~4 dwordx4 loads in flight per wave
// => 3.3 TB/s effective (latency-bound, not BW-bound). The __syncthreads()
// between the loads and the compute is a scheduling boundary the backend
// cannot sink global loads across: it must issue all 16 global_load_dwordx4,
// then s_waitcnt vmcnt(0) + s_barrier. => 16 outstanding loads per wave,
// single wait. Costs one extra (cheap) barrier per block.
// (Two prior rounds using a 16-operand inline-asm barrier failed to build
// in the container; this version contains no inline asm.)
// __launch_bounds__(256,4): 128-VGPR budget — room for the 64 payload regs.
__global__ __launch_bounds__(256, 4) void ssd_partials(const float4* __restrict__ p,
                                                       const float4* __restrict__ t,
                                                       float* __restrict__ ws) {
    const int tid = threadIdx.x;
    // Each block covers 2048 consecutive float4s.
    const long long base = (long long)blockIdx.x * 2048 + tid;

    float4 a[8], b[8];
    #pragma unroll
    for (int u = 0; u < 8; ++u) a[u] = p[base + u * 256];
    #pragma unroll
    for (int u = 0; u < 8; ++u) b[u] = t[base + u * 256];

    // Scheduling fence: all 16 loads issued before this point; backend emits
    // s_waitcnt vmcnt(0) + s_barrier here. Keeps 64 payload VGPRs live.
    __syncthreads();

    float acc0 = 0.f, acc1 = 0.f, acc2 = 0.f, acc3 = 0.f;
    #pragma unroll
    for (int u = 0; u < 8; ++u) {
        float dx = a[u].x - b[u].x; acc0 += dx * dx;
        float dy = a[u].y - b[u].y; acc1 += dy * dy;
        float dz = a[u].z - b[u].z; acc2 += dz * dz;
        float dw = a[u].w - b[u].w; acc3 += dw * dw;
    }
    float acc = (acc0 + acc1) + (acc2 + acc3);

    // wave-64 reduce
    #pragma unroll
    for (int off = 32; off > 0; off >>= 1)
        acc += __shfl_down(acc, off, 64);

    __shared__ float wave_sums[4];
    const int lane = tid & 63;
    const int wave = tid >> 6;
    if (lane == 0) wave_sums[wave] = acc;
    __syncthreads();

    if (tid == 0)
        ws[blockIdx.x] = (wave_sums[0] + wave_sums[1]) + (wave_sums[2] + wave_sums[3]);
}

// Kernel 2: reduce 2047 partials -> out[0] = sum * scale.
// Single block of 256; every ws slot read was written by kernel 1.
// Deterministic read order => bit-exact across runs.
__global__ __launch_bounds__(256) void ssd_finalize(const float* __restrict__ ws,
                                                    float* __restrict__ out,
                                                    float scale) {
    const int tid = threadIdx.x;
    float acc = 0.f;
    #pragma unroll
    for (int k = 0; k < 8; ++k) {
        int idx = tid + k * 256;
        if (idx < 2047) acc += ws[idx];
    }

    #pragma unroll
    for (int off = 32; off > 0; off >>= 1)
        acc += __shfl_down(acc, off, 64);

    __shared__ float wave_sums[4];
    const int lane = tid & 63;
    const int wave = tid >> 6;
    if (lane == 0) wave_sums[wave] = acc;
    __syncthreads();

    if (tid == 0)
        out[0] = ((wave_sums[0] + wave_sums[1]) + (wave_sums[2] + wave_sums[3])) * scale;
}

extern "C" void kernel_launch(void* const* d_in, const int* in_sizes, int n_in,
                              void* d_out, int out_size, void* d_ws, size_t ws_size,
                              hipStream_t stream) {
    const float* pred = (const float*)d_in[0];
    const float* targ = (const float*)d_in[1];
    float* out = (float*)d_out;
    float* ws = (float*)d_ws;  // needs 2047 floats = 8188 B

    const int B = 4096;
    const int S = 2047;  // 2*d+1 with d=1023 — slice covers the whole tensor
    const float scale = 1.0f / ((float)S * (float)B);
    // total float4 pairs = B*S*2/4 = 4,192,256 = 2047 * 2048 exactly.

    ssd_partials<<<2047, 256, 0, stream>>>((const float4*)pred,
                                           (const float4*)targ, ws);
    ssd_finalize<<<1, 256, 0, stream>>>(ws, out, scale);
}